// Round 3
// baseline (508.437 us; speedup 1.0000x reference)
//
#include <hip/hip_runtime.h>

// B=4, S=2048 -> M=8192 rows; OUT_F=N=4096; IN_F=K=4096; GROUP=128.
#define K_DIM 4096
#define N_DIM 4096
#define M_DIM 8192

typedef __bf16 bf16;
typedef __attribute__((ext_vector_type(8))) __bf16 bf16x8;
typedef __attribute__((ext_vector_type(16))) float f32x16;
typedef __attribute__((ext_vector_type(4))) float fv4;
typedef __attribute__((ext_vector_type(8))) unsigned short u16x8;

// fp32 -> bf16 round-to-nearest-even
__device__ inline unsigned short f2bf(float f) {
    unsigned u = __builtin_bit_cast(unsigned, f);
    u += 0x7fffu + ((u >> 16) & 1u);
    return (unsigned short)(u >> 16);
}

// ---- prep: blocks [0,8192) convert x (16 floats/thread); [8192,12288) build W ----
// Nontemporal loads (streams never re-read); normal stores (GEMM re-reads from L2/L3).
__global__ __launch_bounds__(256) void prep_kernel(const float* __restrict__ x,
                                                   const float* __restrict__ sw,
                                                   const float* __restrict__ scales,
                                                   unsigned short* __restrict__ oA,
                                                   unsigned short* __restrict__ oW) {
    const int b = blockIdx.x;
    if (b < 8192) {
        const size_t T = (size_t)b * 256 + threadIdx.x;  // 2,097,152 threads * 16 floats
        const fv4* p = (const fv4*)x + T * 4;
        const fv4 a = __builtin_nontemporal_load(p);
        const fv4 c = __builtin_nontemporal_load(p + 1);
        const fv4 d = __builtin_nontemporal_load(p + 2);
        const fv4 e = __builtin_nontemporal_load(p + 3);
        u16x8 v0, v1;
        v0[0] = f2bf(a[0]); v0[1] = f2bf(a[1]); v0[2] = f2bf(a[2]); v0[3] = f2bf(a[3]);
        v0[4] = f2bf(c[0]); v0[5] = f2bf(c[1]); v0[6] = f2bf(c[2]); v0[7] = f2bf(c[3]);
        v1[0] = f2bf(d[0]); v1[1] = f2bf(d[1]); v1[2] = f2bf(d[2]); v1[3] = f2bf(d[3]);
        v1[4] = f2bf(e[0]); v1[5] = f2bf(e[1]); v1[6] = f2bf(e[2]); v1[7] = f2bf(e[3]);
        u16x8* o = (u16x8*)oA + T * 2;
        o[0] = v0; o[1] = v1;
    } else {
        const size_t T = (size_t)(b - 8192) * 256 + threadIdx.x;  // 1,048,576 threads
        const float s = scales[T >> 3];  // 16 floats/thread, 128/group -> T/8
        const fv4* p = (const fv4*)sw + T * 4;
        const fv4 a = __builtin_nontemporal_load(p);
        const fv4 c = __builtin_nontemporal_load(p + 1);
        const fv4 d = __builtin_nontemporal_load(p + 2);
        const fv4 e = __builtin_nontemporal_load(p + 3);
        u16x8 v0, v1;
        v0[0] = f2bf(a[0] * s); v0[1] = f2bf(a[1] * s); v0[2] = f2bf(a[2] * s); v0[3] = f2bf(a[3] * s);
        v0[4] = f2bf(c[0] * s); v0[5] = f2bf(c[1] * s); v0[6] = f2bf(c[2] * s); v0[7] = f2bf(c[3] * s);
        v1[0] = f2bf(d[0] * s); v1[1] = f2bf(d[1] * s); v1[2] = f2bf(d[2] * s); v1[3] = f2bf(d[3] * s);
        v1[4] = f2bf(e[0] * s); v1[5] = f2bf(e[1] * s); v1[6] = f2bf(e[2] * s); v1[7] = f2bf(e[3] * s);
        u16x8* o = (u16x8*)oW + T * 2;
        o[0] = v0; o[1] = v1;
    }
}

__device__ inline void gll16(const bf16* g, bf16* l) {
    __builtin_amdgcn_global_load_lds(
        (const __attribute__((address_space(1))) void*)g,
        (__attribute__((address_space(3))) void*)l, 16, 0, 0);
}

// ---- 256x256x64 8-phase GEMM, 32x32x16 MFMA, counted-lgkm read pipeline ----
// 512 thr = 8 waves (2M x 4N), wave tile 128x64 = 4x2 frags of 32x32.
// LDS 128 KiB: [buf:2][A:16K|B:16K elems], each op split kh0/kh1 (8192 elems =
// 256 rows x 32). Swizzle: stored 16B-slot = logical ^ ((row>>1)&3) -> 2-way
// reads (free, m136); staging LDS-linear, swizzle on global src (rule #21).
// Per group (1 K-tile, 4 phases; reads R1..R4, MFMA_i consumes R_i):
//  P1: issue R1(a01,bv kh0: 8) SB0 R2(a23 kh0: 4); stage B1(g+1)->other buf;
//      BAR; lgkmcnt(4) [R1 done]; 8 MFMA; BAR
//  P2: issue R3(a01h,bvh kh1: 8) + R4(a23h kh1: 4); stage B0(g+2);
//      BAR; lgkmcnt(12) [R2 done]; 8 MFMA; BAR
//  P3: stage A0(g+2) [safe: R2 drained @P2]; BAR; lgkmcnt(0) [R3,R4 done -
//      R4 drain is correctness-critical for P4's A1 stage]; 8 MFMA; BAR
//  P4: stage A1(g+2) [safe: R4 drained @P3]; BAR; lgkmcnt(0); 8 MFMA;
//      vmcnt(6) [tile g+1 complete]; BAR
extern __shared__ __align__(16) bf16 lds[];

#define BAR __builtin_amdgcn_s_barrier()
#define SB0 __builtin_amdgcn_sched_barrier(0)
#define STAGE(gbase, kofs, ldst)                                       \
    do {                                                               \
        gll16((gbase) + (kofs), (ldst));                               \
        gll16((gbase) + (size_t)128 * K_DIM + (kofs), (ldst) + 4096);  \
    } while (0)

__device__ __forceinline__ void mm8(f32x16 (&acc)[4][2], int mib,
                                    bf16x8 (&af)[2][2], bf16x8 (&bv)[2][2]) {
#pragma unroll
    for (int ks = 0; ks < 2; ++ks)
#pragma unroll
        for (int mi = 0; mi < 2; ++mi)
#pragma unroll
            for (int ni = 0; ni < 2; ++ni)
                acc[mib + mi][ni] = __builtin_amdgcn_mfma_f32_32x32x16_bf16(
                    af[mi][ks], bv[ni][ks], acc[mib + mi][ni], 0, 0, 0);
}

template <int BUF, bool I1, bool I2, int VM>
__device__ __forceinline__ void kgroup(f32x16 (&acc)[4][2], const bf16* fA,
                                       const bf16* fB, const int* co, const bf16* gA,
                                       const bf16* gB, bf16* lA, bf16* lB, int ko1,
                                       int ko2) {
    const bf16* rA = fA + BUF * 32768;
    const bf16* rB = fB + BUF * 32768;
    bf16x8 a01[2][2], a23[2][2], bv[2][2], a01h[2][2], a23h[2][2], bvh[2][2];

    // ---- P1 ----
#pragma unroll
    for (int mi = 0; mi < 2; ++mi)
#pragma unroll
        for (int ks = 0; ks < 2; ++ks) a01[mi][ks] = *(const bf16x8*)(rA + mi * 1024 + co[ks]);
#pragma unroll
    for (int ni = 0; ni < 2; ++ni)
#pragma unroll
        for (int ks = 0; ks < 2; ++ks) bv[ni][ks] = *(const bf16x8*)(rB + ni * 1024 + co[ks]);
    SB0;  // pin R1 before R2 in the lgkm FIFO
#pragma unroll
    for (int mi = 0; mi < 2; ++mi)
#pragma unroll
        for (int ks = 0; ks < 2; ++ks)
            a23[mi][ks] = *(const bf16x8*)(rA + (2 + mi) * 1024 + co[ks]);
    if (I1) STAGE(gB, ko1, lB + (1 - BUF) * 32768 + 8192);
    BAR;
    asm volatile("s_waitcnt lgkmcnt(4)" ::: "memory"); SB0;
    __builtin_amdgcn_s_setprio(1); mm8(acc, 0, a01, bv); __builtin_amdgcn_s_setprio(0);
    BAR;

    // ---- P2 ----
#pragma unroll
    for (int mi = 0; mi < 2; ++mi)
#pragma unroll
        for (int ks = 0; ks < 2; ++ks)
            a01h[mi][ks] = *(const bf16x8*)(rA + 8192 + mi * 1024 + co[ks]);
#pragma unroll
    for (int ni = 0; ni < 2; ++ni)
#pragma unroll
        for (int ks = 0; ks < 2; ++ks)
            bvh[ni][ks] = *(const bf16x8*)(rB + 8192 + ni * 1024 + co[ks]);
#pragma unroll
    for (int mi = 0; mi < 2; ++mi)
#pragma unroll
        for (int ks = 0; ks < 2; ++ks)
            a23h[mi][ks] = *(const bf16x8*)(rA + 8192 + (2 + mi) * 1024 + co[ks]);
    if (I2) STAGE(gB, ko2, lB + BUF * 32768);
    BAR;
    asm volatile("s_waitcnt lgkmcnt(12)" ::: "memory"); SB0;
    __builtin_amdgcn_s_setprio(1); mm8(acc, 2, a23, bv); __builtin_amdgcn_s_setprio(0);
    BAR;

    // ---- P3 ----
    if (I2) STAGE(gA, ko2, lA + BUF * 32768);
    BAR;
    asm volatile("s_waitcnt lgkmcnt(0)" ::: "memory"); SB0;
    __builtin_amdgcn_s_setprio(1); mm8(acc, 0, a01h, bvh); __builtin_amdgcn_s_setprio(0);
    BAR;

    // ---- P4 ----
    if (I2) STAGE(gA, ko2 + 32, lA + BUF * 32768 + 8192);
    BAR;
    asm volatile("s_waitcnt lgkmcnt(0)" ::: "memory"); SB0;
    __builtin_amdgcn_s_setprio(1); mm8(acc, 2, a23h, bvh); __builtin_amdgcn_s_setprio(0);
    if (VM == 6) asm volatile("s_waitcnt vmcnt(6)" ::: "memory");
    if (VM == 0) asm volatile("s_waitcnt vmcnt(0)" ::: "memory");
    BAR;
}

__global__ __launch_bounds__(512, 2) void gemm_bt_kernel(const bf16* __restrict__ A,
                                                         const bf16* __restrict__ W,
                                                         float* __restrict__ C) {
    // XCD-aware swizzle (512 blocks, 512%8==0 -> bijective)
    const int raw = blockIdx.x;
    const int swz = (raw & 7) * 64 + (raw >> 3);
    const int m0 = (swz >> 4) * 256;
    const int n0 = (swz & 15) * 256;

    const int t = threadIdx.x;
    const int lane = t & 63;
    const int w = t >> 6;
    const int wm = w >> 2;  // 0..1
    const int wn = w & 3;   // 0..3
    const int l31 = lane & 31;
    const int hl = lane >> 5;

    // Staging: granule s = j*512+t -> row s>>2, stored slot s&3,
    // logical slot = (s&3)^((row)>>1&3) = (t&3)^((t>>3)&3) for both j.
    const int srow = t >> 2;
    const int slb = ((t & 3) ^ ((t >> 3) & 3)) * 8;
    const bf16* gA = A + (size_t)(m0 + srow) * K_DIM + slb;
    const bf16* gB = W + (size_t)(n0 + srow) * K_DIM + slb;
    bf16* lA = lds + t * 8;
    bf16* lB = lds + 16384 + t * 8;

    // Fragment reads (32x32 frag): row = base + l31, bases mult of 32 ->
    // (row>>1)&3 == (l31>>1)&3; logical slot = ks*2 + hl.
    int co[2];
#pragma unroll
    for (int ks = 0; ks < 2; ++ks) co[ks] = ((ks * 2 + hl) ^ ((l31 >> 1) & 3)) * 8;
    const bf16* fA = lds + (wm * 128 + l31) * 32;
    const bf16* fB = lds + 16384 + (wn * 64 + l31) * 32;

    f32x16 acc[4][2] = {};

    // Prologue: tile0 {A0,B0,A1,B1} + tile1 {B0,A0,A1} (steady-state order).
    STAGE(gA, 0, lA);
    STAGE(gB, 0, lB);
    STAGE(gA, 32, lA + 8192);
    STAGE(gB, 32, lB + 8192);
    STAGE(gB, 64, lB + 32768);
    STAGE(gA, 64, lA + 32768);
    STAGE(gA, 96, lA + 32768 + 8192);
    asm volatile("s_waitcnt vmcnt(6)" ::: "memory");  // tile0 resident
    BAR;

    int ko1 = 96;   // group g stages B1(g+1) at (g+1)*64+32
    int ko2 = 128;  // group g stages tile g+2 at (g+2)*64
#pragma unroll 1
    for (int gg = 0; gg < 31; ++gg) {  // groups 0..61
        kgroup<0, true, true, 6>(acc, fA, fB, co, gA, gB, lA, lB, ko1, ko2);
        ko1 += 64; ko2 += 64;
        kgroup<1, true, true, 6>(acc, fA, fB, co, gA, gB, lA, lB, ko1, ko2);
        ko1 += 64; ko2 += 64;
    }
    kgroup<0, true, false, 0>(acc, fA, fB, co, gA, gB, lA, lB, ko1, ko2);   // g=62
    kgroup<1, false, false, -1>(acc, fA, fB, co, gA, gB, lA, lB, 0, 0);     // g=63

    // Epilogue: 32x32 C/D layout col=lane&31, row=(r&3)+8*(r>>2)+4*(lane>>5)
    // [m74/m101-verified]
    float* Cb = C + (size_t)(m0 + wm * 128) * N_DIM + n0 + wn * 64;
#pragma unroll
    for (int mi = 0; mi < 4; ++mi)
#pragma unroll
        for (int ni = 0; ni < 2; ++ni)
#pragma unroll
            for (int r = 0; r < 16; ++r) {
                const int row = mi * 32 + (r & 3) + 8 * (r >> 2) + 4 * hl;
                Cb[(size_t)row * N_DIM + ni * 32 + l31] = acc[mi][ni][r];
            }
}

extern "C" void kernel_launch(void* const* d_in, const int* in_sizes, int n_in,
                              void* d_out, int out_size, void* d_ws, size_t ws_size,
                              hipStream_t stream) {
    const float* x = (const float*)d_in[0];
    const float* sw = (const float*)d_in[1];
    const float* scales = (const float*)d_in[2];
    float* out = (float*)d_out;

    bf16* Abf = (bf16*)d_ws;                                       // 64 MB
    bf16* Wbf = (bf16*)((char*)d_ws + (size_t)M_DIM * K_DIM * 2);  // +32 MB

    static int lds_set = 0;
    if (!lds_set) {
        (void)hipFuncSetAttribute((const void*)gemm_bt_kernel,
                                  hipFuncAttributeMaxDynamicSharedMemorySize, 131072);
        lds_set = 1;
    }

    prep_kernel<<<12288, 256, 0, stream>>>(x, sw, scales,
                                           (unsigned short*)Abf, (unsigned short*)Wbf);

    gemm_bt_kernel<<<dim3(N_DIM / 256 * (M_DIM / 256)), 512, 131072, stream>>>(Abf, Wbf, out);
}